// Round 2
// baseline (40.086 us; speedup 1.0000x reference)
//
#include <hip/hip_runtime.h>
#include <math.h>

// Problem constants: B=2, N=1024, H=128, E=32
#define NN 1024
#define HH 128
#define EE 32
#define NPB 8   // nodes per block in gfeat2

// Math (node-local fusion, no cross-block deps):
//   t[bn,o]  = sum_h nf[bn,h]*Wt[o,h] + bt[o]            (LDS-resident per block)
//   g[bn,e'] : e'=0..31  -> sum_o t[bn,o]*W1[e,o]     + b1[e]   (i-half, b1 folded)
//              e'=32..63 -> sum_o t[bn,o]*W1[e,128+o]           (j-half)
//   ew(n,m) = b2 + sum_e relu(g[n,e] + g[m,32+e]) * W2[e]
//   out     = sigmoid(ew) * adj[n,m]   (exactly 0 where adj==0 -> skip inner loop)
//
// ws layout (floats): gall[2048*64]

__global__ __launch_bounds__(256) void gfeat2_kernel(
    const float* __restrict__ nf, const float* __restrict__ Wt,
    const float* __restrict__ bt, const float* __restrict__ W1,
    const float* __restrict__ b1, float* __restrict__ gall)
{
    __shared__ float s_nf[NPB * 128];
    __shared__ float s_t[NPB * 128];

    const int tid = threadIdx.x;
    const int nb  = blockIdx.x * NPB;   // first node (bn-flat) of this block

    // Phase A: load 8 node rows of nf (1024 floats) coalesced
    {
        const float4 v = *reinterpret_cast<const float4*>(nf + nb * 128 + tid * 4);
        *reinterpret_cast<float4*>(s_nf + tid * 4) = v;
    }
    __syncthreads();

    // Phase B: t = nf@Wt^T + bt. 1024 outputs, 4 per thread.
    // Per wave: n uniform (broadcast s_nf), lanes span consecutive o rows of Wt
    // (rows L1/L2-cached & reused across waves).
    #pragma unroll
    for (int r = 0; r < 4; ++r) {
        const int idx = tid + r * 256;
        const int n = idx >> 7;          // wave-uniform
        const int o = idx & 127;
        const float4* __restrict__ wrow = reinterpret_cast<const float4*>(Wt + o * 128);
        const float4* __restrict__ nrow = reinterpret_cast<const float4*>(s_nf + n * 128);
        float4 a4 = make_float4(0.f, 0.f, 0.f, 0.f);
        #pragma unroll 8
        for (int hc = 0; hc < 32; ++hc) {
            const float4 w  = wrow[hc];
            const float4 nv = nrow[hc];
            a4.x = fmaf(w.x, nv.x, a4.x);
            a4.y = fmaf(w.y, nv.y, a4.y);
            a4.z = fmaf(w.z, nv.z, a4.z);
            a4.w = fmaf(w.w, nv.w, a4.w);
        }
        s_t[n * 128 + o] = (a4.x + a4.y) + (a4.z + a4.w) + bt[o];
    }
    __syncthreads();

    // Phase C: g = t@W1'^T (+b1 on i-half). 512 outputs, 2 per thread.
    #pragma unroll
    for (int r = 0; r < 2; ++r) {
        const int idx  = tid + r * 256;
        const int n    = idx >> 6;       // wave-uniform
        const int ep   = idx & 63;
        const int e    = ep & 31;
        const int half = ep >> 5;
        const float4* __restrict__ w1row =
            reinterpret_cast<const float4*>(W1 + e * 256 + half * 128);
        const float4* __restrict__ trow =
            reinterpret_cast<const float4*>(s_t + n * 128);
        float4 a4 = make_float4(0.f, 0.f, 0.f, 0.f);
        #pragma unroll 8
        for (int oc = 0; oc < 32; ++oc) {
            const float4 w  = w1row[oc];
            const float4 tv = trow[oc];
            a4.x = fmaf(w.x, tv.x, a4.x);
            a4.y = fmaf(w.y, tv.y, a4.y);
            a4.z = fmaf(w.z, tv.z, a4.z);
            a4.w = fmaf(w.w, tv.w, a4.w);
        }
        float acc = (a4.x + a4.y) + (a4.z + a4.w);
        if (half == 0) acc += b1[e];
        gall[(nb + n) * 64 + ep] = acc;  // lanes consecutive ep -> coalesced
    }
}

// One block per (b, n) output row; thread handles 4 m's via float4.
__global__ __launch_bounds__(256) void edge_kernel(
    const float* __restrict__ adj, const float* __restrict__ gall,
    const float* __restrict__ W2, const float* __restrict__ b2,
    float* __restrict__ out)
{
    const int n   = blockIdx.x;
    const int b   = blockIdx.y;
    const int tid = threadIdx.x;

    // Issue the adj load first so it overlaps the LDS fill + barrier.
    const int m0 = tid * 4;
    const float4 a4 = *reinterpret_cast<const float4*>(adj + n * NN + m0);

    __shared__ float s_u[32];   // g[n, 0:32]  (hi + b1, i-half)
    __shared__ float s_w2[32];
    if (tid < 32) {
        s_u[tid]  = gall[(b * NN + n) * 64 + tid];
        s_w2[tid] = W2[tid];
    }
    __syncthreads();
    const float b2v = b2[0];

    float4 r4;
    const float* ap = &a4.x;
    float* rp = &r4.x;

    #pragma unroll
    for (int cc = 0; cc < 4; ++cc) {
        const float a = ap[cc];
        float r = 0.f;
        if (a != 0.f) {
            const float* gj = gall + (b * NN + m0 + cc) * 64 + 32;
            float ew = b2v;
            #pragma unroll
            for (int j = 0; j < 8; ++j) {
                const float4 gv = *reinterpret_cast<const float4*>(gj + 4 * j);
                const float v0 = fmaxf(s_u[4 * j + 0] + gv.x, 0.f);
                const float v1 = fmaxf(s_u[4 * j + 1] + gv.y, 0.f);
                const float v2 = fmaxf(s_u[4 * j + 2] + gv.z, 0.f);
                const float v3 = fmaxf(s_u[4 * j + 3] + gv.w, 0.f);
                ew = fmaf(v0, s_w2[4 * j + 0], ew);
                ew = fmaf(v1, s_w2[4 * j + 1], ew);
                ew = fmaf(v2, s_w2[4 * j + 2], ew);
                ew = fmaf(v3, s_w2[4 * j + 3], ew);
            }
            r = a / (1.f + __expf(-ew));
        }
        rp[cc] = r;
    }
    *reinterpret_cast<float4*>(out + (size_t)(b * NN + n) * NN + m0) = r4;
}

extern "C" void kernel_launch(void* const* d_in, const int* in_sizes, int n_in,
                              void* d_out, int out_size, void* d_ws, size_t ws_size,
                              hipStream_t stream)
{
    const float* nf  = (const float*)d_in[0];
    const float* adj = (const float*)d_in[1];
    const float* Wt  = (const float*)d_in[2];
    const float* bt  = (const float*)d_in[3];
    const float* W1  = (const float*)d_in[4];
    const float* b1  = (const float*)d_in[5];
    const float* W2  = (const float*)d_in[6];
    const float* b2  = (const float*)d_in[7];
    float* out = (float*)d_out;

    float* gall = (float*)d_ws;   // 2048*64 floats = 512 KB

    hipLaunchKernelGGL(gfeat2_kernel, dim3(2048 / NPB), dim3(256), 0, stream,
                       nf, Wt, bt, W1, b1, gall);
    hipLaunchKernelGGL(edge_kernel, dim3(NN, 2), dim3(256), 0, stream,
                       adj, gall, W2, b2, out);
}